// Round 1
// baseline (224.241 us; speedup 1.0000x reference)
//
#include <hip/hip_runtime.h>
#include <math.h>

// Problem constants (from setup_inputs):
//   src   (8, 3, 512, 512) f32
//   grid1 (8, 32, 8, 16, 16) f32
//   grid2 (8, 27, 8, 16, 16) f32
//   w1 (16,3,1,1) b1 (16)  w2 (1,16,1,1) b2 (1)
//   w3 (16,8,1,1) b3 (16)  w4 (1,16,1,1) b4 (1)
// out (8, 3, 512, 512) f32
#define BATCH 8
#define IMH 512
#define IMW 512
#define HWSZ (IMH * IMW)
#define GD 8
#define GHH 16
#define GWW 16
#define CELLS (GD * GHH * GWW)   // 2048 cells per (batch)

// ---------- transpose grid1: [b][c32][z][y][x] -> [b][z][y][x][c32] ----------
__global__ __launch_bounds__(256) void transpose_g1(const float* __restrict__ g,
                                                    float* __restrict__ t) {
    int idx = blockIdx.x * 256 + threadIdx.x;     // 8*2048*32 = 524288 total
    int c = idx & 31;
    int r = idx >> 5;            // b*2048 + z*256 + y*16 + x
    int x = r & 15;
    int y = (r >> 4) & 15;
    int z = (r >> 8) & 7;
    int b = r >> 11;
    t[idx] = g[((((size_t)b * 32 + c) * 8 + z) * 16 + y) * 16 + x];
}

// ---------- transpose grid2: [b][c27][z][y][x] -> [b][z][y][x][c28] (pad) ----
__global__ __launch_bounds__(256) void transpose_g2(const float* __restrict__ g,
                                                    float* __restrict__ t) {
    int idx = blockIdx.x * 256 + threadIdx.x;     // 8*2048*28 = 458752 total
    int c = idx % 28;
    int r = idx / 28;            // b*2048 + z*256 + y*16 + x
    int x = r & 15;
    int y = (r >> 4) & 15;
    int z = (r >> 8) & 7;
    int b = r >> 11;
    float v = 0.0f;
    if (c < 27)
        v = g[((((size_t)b * 27 + c) * 8 + z) * 16 + y) * 16 + x];
    t[idx] = v;
}

// ---------- fully fused per-pixel pipeline ----------
template <bool TR>
__global__ __launch_bounds__(256) void fused_kernel(
    const float* __restrict__ src,
    const float* __restrict__ g1p,  // TR ? transposed : raw grid1
    const float* __restrict__ g2p,  // TR ? transposed : raw grid2
    const float* __restrict__ w1, const float* __restrict__ b1,
    const float* __restrict__ w2, const float* __restrict__ b2,
    const float* __restrict__ w3, const float* __restrict__ b3,
    const float* __restrict__ w4, const float* __restrict__ b4,
    float* __restrict__ out) {
    int idx = blockIdx.x * 256 + threadIdx.x;     // 8*512*512 pixels
    int w = idx & (IMW - 1);
    int h = (idx >> 9) & (IMH - 1);
    int b = idx >> 18;

    const float* sb = src + (size_t)b * 3 * HWSZ + h * IMW + w;
    float s0 = sb[0];
    float s1 = sb[HWSZ];
    float s2 = sb[2 * HWSZ];

    // ---- guide MLP #1: 3 -> 16 -> 1, relu / tanh ----
    float acc = b2[0];
#pragma unroll
    for (int j = 0; j < 16; ++j) {
        float t = fmaf(w1[j * 3 + 0], s0,
                  fmaf(w1[j * 3 + 1], s1,
                  fmaf(w1[j * 3 + 2], s2, b1[j])));
        acc = fmaf(w2[j], fmaxf(t, 0.0f), acc);
    }
    float g1 = tanhf(acc);

    // ---- spatial interpolation coords (shared by both slices) ----
    float gx = (w - 256.0f) * (1.0f / 256.0f);
    float gy = (h - 256.0f) * (1.0f / 256.0f);
    float fx = fminf(fmaxf((gx + 1.0f) * 0.5f * 15.0f, 0.0f), 15.0f);
    float fy = fminf(fmaxf((gy + 1.0f) * 0.5f * 15.0f, 0.0f), 15.0f);
    int x0 = (int)floorf(fx);
    int y0 = (int)floorf(fy);
    int x1 = min(x0 + 1, 15);
    int y1 = min(y0 + 1, 15);
    float wx = fx - (float)x0;
    float wy = fy - (float)y0;

    // ---- slice 1: trilinear gather of 32 channels from grid1 ----
    float fz = fminf(fmaxf((g1 + 1.0f) * 0.5f * 7.0f, 0.0f), 7.0f);
    int z0 = (int)floorf(fz);
    int z1 = min(z0 + 1, 7);
    float wz = fz - (float)z0;

    float c1[32];
#pragma unroll
    for (int i = 0; i < 32; ++i) c1[i] = 0.0f;

    const float* g1b = g1p + (size_t)b * CELLS * (TR ? 32 : 32);  // raw: b*32*2048 == b*2048*32
#pragma unroll
    for (int dz = 0; dz < 2; ++dz) {
        int zi = dz ? z1 : z0;
        float wgz = dz ? wz : 1.0f - wz;
#pragma unroll
        for (int dy = 0; dy < 2; ++dy) {
            int yi = dy ? y1 : y0;
            float wgzy = wgz * (dy ? wy : 1.0f - wy);
#pragma unroll
            for (int dx = 0; dx < 2; ++dx) {
                int xi = dx ? x1 : x0;
                float wgt = wgzy * (dx ? wx : 1.0f - wx);
                if (TR) {
                    const float4* p =
                        (const float4*)(g1b + ((size_t)((zi * 16 + yi) * 16 + xi)) * 32);
#pragma unroll
                    for (int i = 0; i < 8; ++i) {
                        float4 v = p[i];
                        c1[4 * i + 0] = fmaf(v.x, wgt, c1[4 * i + 0]);
                        c1[4 * i + 1] = fmaf(v.y, wgt, c1[4 * i + 1]);
                        c1[4 * i + 2] = fmaf(v.z, wgt, c1[4 * i + 2]);
                        c1[4 * i + 3] = fmaf(v.w, wgt, c1[4 * i + 3]);
                    }
                } else {
                    const float* p = g1b + (zi * 256 + yi * 16 + xi);
#pragma unroll
                    for (int c = 0; c < 32; ++c)
                        c1[c] = fmaf(p[(size_t)c * CELLS], wgt, c1[c]);
                }
            }
        }
    }

    // ---- affine #1: hidden[o] = relu(sum_i c1[i*8+o]*src_i + c1[24+o]) ----
    float hid[8];
#pragma unroll
    for (int o = 0; o < 8; ++o) {
        float t = fmaf(c1[o], s0,
                  fmaf(c1[8 + o], s1,
                  fmaf(c1[16 + o], s2, c1[24 + o])));
        hid[o] = fmaxf(t, 0.0f);
    }

    // ---- guide MLP #2: 8 -> 16 -> 1 ----
    float acc2 = b4[0];
#pragma unroll
    for (int j = 0; j < 16; ++j) {
        float t = b3[j];
#pragma unroll
        for (int i = 0; i < 8; ++i) t = fmaf(w3[j * 8 + i], hid[i], t);
        acc2 = fmaf(w4[j], fmaxf(t, 0.0f), acc2);
    }
    float g2 = tanhf(acc2);

    // ---- slice 2: trilinear gather of 27 channels from grid2 ----
    float fz2 = fminf(fmaxf((g2 + 1.0f) * 0.5f * 7.0f, 0.0f), 7.0f);
    int z0b = (int)floorf(fz2);
    int z1b = min(z0b + 1, 7);
    float wz2 = fz2 - (float)z0b;

    float c2[28];
#pragma unroll
    for (int i = 0; i < 28; ++i) c2[i] = 0.0f;

    const float* g2b = g2p + (size_t)b * CELLS * (TR ? 28 : 27);
#pragma unroll
    for (int dz = 0; dz < 2; ++dz) {
        int zi = dz ? z1b : z0b;
        float wgz = dz ? wz2 : 1.0f - wz2;
#pragma unroll
        for (int dy = 0; dy < 2; ++dy) {
            int yi = dy ? y1 : y0;
            float wgzy = wgz * (dy ? wy : 1.0f - wy);
#pragma unroll
            for (int dx = 0; dx < 2; ++dx) {
                int xi = dx ? x1 : x0;
                float wgt = wgzy * (dx ? wx : 1.0f - wx);
                if (TR) {
                    const float4* p =
                        (const float4*)(g2b + ((size_t)((zi * 16 + yi) * 16 + xi)) * 28);
#pragma unroll
                    for (int i = 0; i < 7; ++i) {
                        float4 v = p[i];
                        c2[4 * i + 0] = fmaf(v.x, wgt, c2[4 * i + 0]);
                        c2[4 * i + 1] = fmaf(v.y, wgt, c2[4 * i + 1]);
                        c2[4 * i + 2] = fmaf(v.z, wgt, c2[4 * i + 2]);
                        c2[4 * i + 3] = fmaf(v.w, wgt, c2[4 * i + 3]);
                    }
                } else {
                    const float* p = g2b + (zi * 256 + yi * 16 + xi);
#pragma unroll
                    for (int c = 0; c < 27; ++c)
                        c2[c] = fmaf(p[(size_t)c * CELLS], wgt, c2[c]);
                }
            }
        }
    }

    // ---- affine #2: out[o] = sum_i c2[i*3+o]*hid[i] + c2[24+o] ----
    float* ob = out + (size_t)b * 3 * HWSZ + h * IMW + w;
#pragma unroll
    for (int o = 0; o < 3; ++o) {
        float t = c2[24 + o];
#pragma unroll
        for (int i = 0; i < 8; ++i) t = fmaf(c2[i * 3 + o], hid[i], t);
        ob[(size_t)o * HWSZ] = t;
    }
}

extern "C" void kernel_launch(void* const* d_in, const int* in_sizes, int n_in,
                              void* d_out, int out_size, void* d_ws, size_t ws_size,
                              hipStream_t stream) {
    const float* src   = (const float*)d_in[0];
    const float* grid1 = (const float*)d_in[1];
    const float* grid2 = (const float*)d_in[2];
    const float* w1 = (const float*)d_in[3];
    const float* b1 = (const float*)d_in[4];
    const float* w2 = (const float*)d_in[5];
    const float* b2 = (const float*)d_in[6];
    const float* w3 = (const float*)d_in[7];
    const float* b3 = (const float*)d_in[8];
    const float* w4 = (const float*)d_in[9];
    const float* b4 = (const float*)d_in[10];
    float* out = (float*)d_out;

    const size_t t1_elems = (size_t)BATCH * CELLS * 32;  // 524288
    const size_t t2_elems = (size_t)BATCH * CELLS * 28;  // 458752
    const size_t ws_needed = (t1_elems + t2_elems) * sizeof(float);

    const int npix = BATCH * HWSZ;          // 2,097,152
    const int nblk = npix / 256;            // 8192

    if (ws_size >= ws_needed) {
        float* t1 = (float*)d_ws;
        float* t2 = t1 + t1_elems;
        transpose_g1<<<(int)(t1_elems / 256), 256, 0, stream>>>(grid1, t1);
        transpose_g2<<<(int)(t2_elems / 256), 256, 0, stream>>>(grid2, t2);
        fused_kernel<true><<<nblk, 256, 0, stream>>>(
            src, t1, t2, w1, b1, w2, b2, w3, b3, w4, b4, out);
    } else {
        fused_kernel<false><<<nblk, 256, 0, stream>>>(
            src, grid1, grid2, w1, b1, w2, b2, w3, b3, w4, b4, out);
    }
}

// Round 2
// 133.927 us; speedup vs baseline: 1.6744x; 1.6744x over previous
//
#include <hip/hip_runtime.h>
#include <math.h>

// src (8,3,512,512) f32 | grid1 (8,32,8,16,16) | grid2 (8,27,8,16,16)
// out (8,3,512,512) f32
#define BATCH 8
#define IMH 512
#define IMW 512
#define HWSZ (IMH * IMW)
#define XSPAN 9              // x-cells covered by one half-row block
#define CPAD 36              // LDS channel stride (36%32=4 -> z spreads banks; 16B aligned)
#define L_CELLS (XSPAN * 8)  // 72 (x,z) cells
#define LSLOT (L_CELLS * CPAD)

__device__ __forceinline__ float fast_tanh(float x) {
    // tanh = 1 - 2/(e^{2x}+1); exact at both saturations, ~1e-5 abs err.
    float e = __expf(2.0f * x);
    return fmaf(-2.0f, __builtin_amdgcn_rcpf(e + 1.0f), 1.0f);
}

// ---- one-shot transpose: grid1 -> [b][y][x][z][32], grid2 -> [b][y][x][z][28] (c=27 pad=0)
__global__ __launch_bounds__(256) void transpose_both(const float* __restrict__ g1,
                                                      const float* __restrict__ g2,
                                                      float* __restrict__ t1,
                                                      float* __restrict__ t2) {
    int idx = blockIdx.x * 256 + threadIdx.x;  // 983040 total
    if (idx < 524288) {                        // grid1: [b][c][z][y][x] linear read
        int x = idx & 15, y = (idx >> 4) & 15, z = (idx >> 8) & 7;
        int c = (idx >> 11) & 31, b = idx >> 16;
        t1[((((b * 16 + y) * 16 + x) * 8 + z) << 5) + c] = g1[idx];
    } else if (idx < 966656) {                 // grid2
        int j = idx - 524288;
        int x = j & 15, y = (j >> 4) & 15, z = (j >> 8) & 7;
        int r = j >> 11;
        int c = r % 27, b = r / 27;
        t2[(((b * 16 + y) * 16 + x) * 8 + z) * 28 + c] = g2[j];
    } else {                                   // zero the pad channel
        int k = idx - 966656;                  // cell index b*2048+y*128+x*8+z (any order ok)
        t2[k * 28 + 27] = 0.0f;
    }
}

// ---- fused pipeline; one block = one half-row (256 pixels) of one batch image
template <bool TR>
__global__ __launch_bounds__(256, 4) void fused2(
    const float* __restrict__ src,
    const float* __restrict__ g1p,  // TR ? transposed : raw
    const float* __restrict__ g2p,
    const float* __restrict__ w1, const float* __restrict__ b1,
    const float* __restrict__ w2, const float* __restrict__ b2,
    const float* __restrict__ w3, const float* __restrict__ b3,
    const float* __restrict__ w4, const float* __restrict__ b4,
    float* __restrict__ out) {
    __shared__ __align__(16) float L1s[LSLOT];  // y-lerped grid1 slab [x][z][36]
    __shared__ __align__(16) float L2s[LSLOT];  // y-lerped grid2 slab [x][z][36]

    int tid = threadIdx.x;
    int half = blockIdx.x & 1;
    int h = (blockIdx.x >> 1) & 511;
    int b = blockIdx.x >> 10;
    int w0 = half << 8;
    int x_lo = half ? 7 : 0;  // x-cells [x_lo, x_lo+8] cover this half-row

    float fy = (float)h * (15.0f / 512.0f);
    int y0 = (int)fy;
    float wy = fy - (float)y0;
    int y1 = y0 + 1;  // fy <= 14.97 so y0 <= 14

    // ---------------- stage y-interpolated slabs into LDS ----------------
    if (TR) {
        const float* p1a = g1p + ((((size_t)b * 16 + y0) * 16 + x_lo) * 8) * 32;
        const float* p1b = g1p + ((((size_t)b * 16 + y1) * 16 + x_lo) * 8) * 32;
        for (int t = tid; t < L_CELLS * 8; t += 256) {  // 576 float4s
            int g = t & 7, cell = t >> 3;
            float4 v0 = *(const float4*)(p1a + (size_t)t * 4);
            float4 v1 = *(const float4*)(p1b + (size_t)t * 4);
            float4 r;
            r.x = fmaf(wy, v1.x - v0.x, v0.x);
            r.y = fmaf(wy, v1.y - v0.y, v0.y);
            r.z = fmaf(wy, v1.z - v0.z, v0.z);
            r.w = fmaf(wy, v1.w - v0.w, v0.w);
            *(float4*)&L1s[cell * CPAD + 4 * g] = r;
        }
        const float* p2a = g2p + ((((size_t)b * 16 + y0) * 16 + x_lo) * 8) * 28;
        const float* p2b = g2p + ((((size_t)b * 16 + y1) * 16 + x_lo) * 8) * 28;
        for (int t = tid; t < L_CELLS * 7; t += 256) {  // 504 float4s
            int g = t % 7, cell = t / 7;
            float4 v0 = *(const float4*)(p2a + (size_t)t * 4);
            float4 v1 = *(const float4*)(p2b + (size_t)t * 4);
            float4 r;
            r.x = fmaf(wy, v1.x - v0.x, v0.x);
            r.y = fmaf(wy, v1.y - v0.y, v0.y);
            r.z = fmaf(wy, v1.z - v0.z, v0.z);
            r.w = fmaf(wy, v1.w - v0.w, v0.w);
            *(float4*)&L2s[cell * CPAD + 4 * g] = r;
        }
    } else {  // fallback: stage straight from raw [b][c][z][y][x] (scalar, slow, correct)
        for (int t = tid; t < L_CELLS * 32; t += 256) {
            int c = t & 31, cell = t >> 5;
            int z = cell & 7, xj = cell >> 3;
            size_t o0 = ((((size_t)b * 32 + c) * 8 + z) * 16 + y0) * 16 + (x_lo + xj);
            float v0 = g1p[o0], v1 = g1p[o0 + 16];
            L1s[cell * CPAD + c] = fmaf(wy, v1 - v0, v0);
        }
        for (int t = tid; t < L_CELLS * 28; t += 256) {
            int c = t % 28, cell = t / 28;
            int z = cell & 7, xj = cell >> 3;
            float v = 0.0f;
            if (c < 27) {
                size_t o0 = ((((size_t)b * 27 + c) * 8 + z) * 16 + y0) * 16 + (x_lo + xj);
                v = fmaf(wy, g2p[o0 + 16] - g2p[o0], g2p[o0]);
            }
            L2s[cell * CPAD + c] = v;
        }
    }
    __syncthreads();

    // ---------------- per-pixel pipeline ----------------
    int w = w0 + tid;
    const float* sb = src + (size_t)b * 3 * HWSZ + h * IMW + w;
    float s0 = sb[0];
    float s1 = sb[HWSZ];
    float s2 = sb[2 * HWSZ];

    // guide MLP #1: 3 -> 16 -> 1
    float acc = b2[0];
#pragma unroll
    for (int j = 0; j < 16; ++j) {
        float t = fmaf(w1[j * 3 + 0], s0,
                  fmaf(w1[j * 3 + 1], s1,
                  fmaf(w1[j * 3 + 2], s2, b1[j])));
        acc = fmaf(w2[j], fmaxf(t, 0.0f), acc);
    }
    float fz = fmaf(fast_tanh(acc), 3.5f, 3.5f);
    fz = fminf(fmaxf(fz, 0.0f), 7.0f);
    int z0 = min((int)fz, 6);          // z0=7 case folded into wz=1 (identical result)
    float wz = fz - (float)z0;

    float fx = (float)w * (15.0f / 512.0f);
    int x0 = (int)fx;
    float wx = fx - (float)x0;
    int a00 = ((x0 - x_lo) * 8 + z0) * CPAD;

    float w11v = wx * wz;
    float w10v = wx - w11v;
    float w01v = wz - w11v;
    float w00v = 1.0f - wx - wz + w11v;

    // slice 1: bilinear (x,z) over 32 channels
    float c1[32];
#pragma unroll
    for (int i = 0; i < 8; ++i) {
        float4 v00 = *(const float4*)&L1s[a00 + 4 * i];
        float4 v01 = *(const float4*)&L1s[a00 + CPAD + 4 * i];
        float4 v10 = *(const float4*)&L1s[a00 + 8 * CPAD + 4 * i];
        float4 v11 = *(const float4*)&L1s[a00 + 9 * CPAD + 4 * i];
        c1[4 * i + 0] = fmaf(v00.x, w00v, fmaf(v01.x, w01v, fmaf(v10.x, w10v, v11.x * w11v)));
        c1[4 * i + 1] = fmaf(v00.y, w00v, fmaf(v01.y, w01v, fmaf(v10.y, w10v, v11.y * w11v)));
        c1[4 * i + 2] = fmaf(v00.z, w00v, fmaf(v01.z, w01v, fmaf(v10.z, w10v, v11.z * w11v)));
        c1[4 * i + 3] = fmaf(v00.w, w00v, fmaf(v01.w, w01v, fmaf(v10.w, w10v, v11.w * w11v)));
    }

    // affine #1: hidden = relu(coeff1 * src)
    float hid[8];
#pragma unroll
    for (int o = 0; o < 8; ++o) {
        float t = fmaf(c1[o], s0,
                  fmaf(c1[8 + o], s1,
                  fmaf(c1[16 + o], s2, c1[24 + o])));
        hid[o] = fmaxf(t, 0.0f);
    }

    // guide MLP #2: 8 -> 16 -> 1
    float acc2 = b4[0];
#pragma unroll
    for (int j = 0; j < 16; ++j) {
        float t = b3[j];
#pragma unroll
        for (int i = 0; i < 8; ++i) t = fmaf(w3[j * 8 + i], hid[i], t);
        acc2 = fmaf(w4[j], fmaxf(t, 0.0f), acc2);
    }
    float fz2 = fmaf(fast_tanh(acc2), 3.5f, 3.5f);
    fz2 = fminf(fmaxf(fz2, 0.0f), 7.0f);
    int z0b = min((int)fz2, 6);
    float wz2 = fz2 - (float)z0b;

    int a00b = ((x0 - x_lo) * 8 + z0b) * CPAD;
    float u11 = wx * wz2;
    float u10 = wx - u11;
    float u01 = wz2 - u11;
    float u00 = 1.0f - wx - wz2 + u11;

    // slice 2: bilinear (x,z) over 28 channels (27 real + pad)
    float c2[28];
#pragma unroll
    for (int i = 0; i < 7; ++i) {
        float4 v00 = *(const float4*)&L2s[a00b + 4 * i];
        float4 v01 = *(const float4*)&L2s[a00b + CPAD + 4 * i];
        float4 v10 = *(const float4*)&L2s[a00b + 8 * CPAD + 4 * i];
        float4 v11 = *(const float4*)&L2s[a00b + 9 * CPAD + 4 * i];
        c2[4 * i + 0] = fmaf(v00.x, u00, fmaf(v01.x, u01, fmaf(v10.x, u10, v11.x * u11)));
        c2[4 * i + 1] = fmaf(v00.y, u00, fmaf(v01.y, u01, fmaf(v10.y, u10, v11.y * u11)));
        c2[4 * i + 2] = fmaf(v00.z, u00, fmaf(v01.z, u01, fmaf(v10.z, u10, v11.z * u11)));
        c2[4 * i + 3] = fmaf(v00.w, u00, fmaf(v01.w, u01, fmaf(v10.w, u10, v11.w * u11)));
    }

    // affine #2
    float* ob = out + (size_t)b * 3 * HWSZ + h * IMW + w;
#pragma unroll
    for (int o = 0; o < 3; ++o) {
        float t = c2[24 + o];
#pragma unroll
        for (int i = 0; i < 8; ++i) t = fmaf(c2[i * 3 + o], hid[i], t);
        ob[(size_t)o * HWSZ] = t;
    }
}

extern "C" void kernel_launch(void* const* d_in, const int* in_sizes, int n_in,
                              void* d_out, int out_size, void* d_ws, size_t ws_size,
                              hipStream_t stream) {
    const float* src   = (const float*)d_in[0];
    const float* grid1 = (const float*)d_in[1];
    const float* grid2 = (const float*)d_in[2];
    const float* w1 = (const float*)d_in[3];
    const float* b1 = (const float*)d_in[4];
    const float* w2 = (const float*)d_in[5];
    const float* b2 = (const float*)d_in[6];
    const float* w3 = (const float*)d_in[7];
    const float* b3 = (const float*)d_in[8];
    const float* w4 = (const float*)d_in[9];
    const float* b4 = (const float*)d_in[10];
    float* out = (float*)d_out;

    const size_t t1_elems = 524288;                       // 8*2048*32
    const size_t t2_elems = (size_t)8 * 2048 * 28;        // 458752 (padded)
    const size_t ws_needed = (t1_elems + t2_elems) * sizeof(float);

    const int nblk = (BATCH * HWSZ) / 256;                // 8192

    if (ws_size >= ws_needed) {
        float* t1 = (float*)d_ws;
        float* t2 = t1 + t1_elems;
        transpose_both<<<3840, 256, 0, stream>>>(grid1, grid2, t1, t2);
        fused2<true><<<nblk, 256, 0, stream>>>(
            src, t1, t2, w1, b1, w2, b2, w3, b3, w4, b4, out);
    } else {
        fused2<false><<<nblk, 256, 0, stream>>>(
            src, grid1, grid2, w1, b1, w2, b2, w3, b3, w4, b4, out);
    }
}